// Round 15
// baseline (226.105 us; speedup 1.0000x reference)
//
#include <hip/hip_runtime.h>
#include <hip/hip_bf16.h>

typedef __hip_bfloat16 bf16;
typedef __attribute__((ext_vector_type(8))) short short8;
typedef __attribute__((ext_vector_type(4))) float f32x4;

static constexpr int NPOS = 65536;  // 64*64*16

__device__ __forceinline__ float bs2f(short s) {
  union { float f; unsigned u; } cv;
  cv.u = ((unsigned)(unsigned short)s) << 16;
  return cv.f;
}
__device__ __forceinline__ short f2bs(float f) {
  bf16 b = __float2bfloat16(f);
  short r;
  __builtin_memcpy(&r, &b, 2);
  return r;
}

// software grid barrier: counter pre-zeroed by k_init; one counter per use.
__device__ __forceinline__ void gbar(unsigned* ctr, unsigned nblk) {
  __syncthreads();  // block's waves done; their stores drained (vmcnt in barrier)
  if (threadIdx.x == 0) {
    __threadfence();  // release: L2 writeback for cross-XCD visibility
    __hip_atomic_fetch_add(ctr, 1u, __ATOMIC_RELEASE, __HIP_MEMORY_SCOPE_AGENT);
    while (__hip_atomic_load(ctr, __ATOMIC_ACQUIRE, __HIP_MEMORY_SCOPE_AGENT) <
           nblk) {
      __builtin_amdgcn_s_sleep(8);
    }
    __threadfence();  // acquire: invalidate L1/L2 before reading others' data
  }
  __syncthreads();
}

__global__ void k_init(unsigned* bar) {
  if (threadIdx.x < 8) bar[threadIdx.x] = 0u;
}

// upsample one (h,w) column (16 z) of channel slab xc; accumulate sum/sq,
// store 16 bf16 to xo.
__device__ __forceinline__ void upsample_col(const float* __restrict__ xc,
                                             int h, int w, float& sum,
                                             float& sq, bf16* __restrict__ xo) {
  float fh = (float)h * (31.0f / 63.0f);
  int ih = (int)fh; if (ih > 30) ih = 30;
  float wh = fh - (float)ih;
  float fw = (float)w * (31.0f / 63.0f);
  int iw = (int)fw; if (iw > 30) iw = 30;
  float ww = fw - (float)iw;
  const float* base = xc + ih * 256 + iw * 8;
  float4 A0 = *(const float4*)(base);
  float4 A1 = *(const float4*)(base + 4);
  float4 B0 = *(const float4*)(base + 8);
  float4 B1 = *(const float4*)(base + 12);
  float4 C0 = *(const float4*)(base + 256);
  float4 C1 = *(const float4*)(base + 260);
  float4 D0 = *(const float4*)(base + 264);
  float4 D1 = *(const float4*)(base + 268);
  float ra[8] = {A0.x, A0.y, A0.z, A0.w, A1.x, A1.y, A1.z, A1.w};
  float rb[8] = {B0.x, B0.y, B0.z, B0.w, B1.x, B1.y, B1.z, B1.w};
  float rc[8] = {C0.x, C0.y, C0.z, C0.w, C1.x, C1.y, C1.z, C1.w};
  float rd[8] = {D0.x, D0.y, D0.z, D0.w, D1.x, D1.y, D1.z, D1.w};
  short8 o0, o1;
#define ZSTEP(zz)                                                              \
  {                                                                            \
    constexpr float fz = (float)(zz) * (7.0f / 15.0f);                         \
    constexpr int izr = (int)fz;                                               \
    constexpr int iz = (izr > 6) ? 6 : izr;                                    \
    constexpr float wz = fz - (float)iz;                                       \
    float va = ra[iz] * (1.f - wz) + ra[iz + 1] * wz;                          \
    float vb = rb[iz] * (1.f - wz) + rb[iz + 1] * wz;                          \
    float vc = rc[iz] * (1.f - wz) + rc[iz + 1] * wz;                          \
    float vd = rd[iz] * (1.f - wz) + rd[iz + 1] * wz;                          \
    float v0 = va * (1.f - ww) + vb * ww;                                      \
    float v1 = vc * (1.f - ww) + vd * ww;                                      \
    float v = v0 * (1.f - wh) + v1 * wh;                                       \
    sum += v; sq += v * v;                                                     \
    if ((zz) < 8) o0[(zz) & 7] = f2bs(v); else o1[(zz) & 7] = f2bs(v);         \
  }
  ZSTEP(0) ZSTEP(1) ZSTEP(2) ZSTEP(3) ZSTEP(4) ZSTEP(5) ZSTEP(6) ZSTEP(7)
  ZSTEP(8) ZSTEP(9) ZSTEP(10) ZSTEP(11) ZSTEP(12) ZSTEP(13) ZSTEP(14) ZSTEP(15)
#undef ZSTEP
  *(short8*)xo = o0;
  *(short8*)(xo + 8) = o1;
}

// Single fused kernel: upsample+stats -> gbar -> MFMA proj -> gbar ->
// flat-27 attention + out-proj. 256 blocks x 256 threads (>=1 block/CU).
__global__ __launch_bounds__(256, 1) void k_fused(
    const float* __restrict__ x, const float* __restrict__ skip,
    const float* __restrict__ Wq, const float* __restrict__ bq,
    const float* __restrict__ Wk, const float* __restrict__ bk,
    const float* __restrict__ Wv, const float* __restrict__ bv,
    const float* __restrict__ Wo, const float* __restrict__ bo,
    const float* __restrict__ rpb,
    bf16* __restrict__ xu, bf16* __restrict__ kbuf, bf16* __restrict__ vbuf,
    bf16* __restrict__ qbuf, float* __restrict__ partials,
    unsigned* __restrict__ bar, float* __restrict__ out) {
  __shared__ float stl[256];
  __shared__ float red1[256];
  __shared__ float red2[256];
  __shared__ float bol[64];
  __shared__ __align__(16) char scratch[47104];
  int tid = threadIdx.x, b = blockIdx.x;

  // ---------------- Phase A: upsample+xu + partial sums ----------------
  float sum = 0.f, sq = 0.f;
  if (b < 128) {
    int c = b >> 1, hh = (b & 1) * 32;
    const float* xc = x + c * 8192;
    bf16* xo = xu + (size_t)c * NPOS;
#pragma unroll
    for (int i = 0; i < 8; i++) {
      int col = i * 256 + tid;
      int h = hh + (col >> 6), w = col & 63;
      upsample_col(xc, h, w, sum, sq, xo + h * 1024 + w * 16);
    }
  } else {
    int bb = b - 128, c = bb >> 1;
    const float4* p =
        (const float4*)(skip + (size_t)c * NPOS + (bb & 1) * 32768);
#pragma unroll 4
    for (int k = 0; k < 32; k++) {
      float4 v = p[k * 256 + tid];
      sum += v.x + v.y + v.z + v.w;
      sq += v.x * v.x + v.y * v.y + v.z * v.z + v.w * v.w;
    }
  }
  red1[tid] = sum; red2[tid] = sq;
  __syncthreads();
  for (int s = 128; s > 0; s >>= 1) {
    if (tid < s) { red1[tid] += red1[tid + s]; red2[tid] += red2[tid + s]; }
    __syncthreads();
  }
  if (tid == 0) { partials[2 * b] = red1[0]; partials[2 * b + 1] = red2[0]; }

  gbar(bar + 0, 256);

  // ---------------- stats (every block, redundant, L2-hot) ----------------
  if (tid < 128) {
    int isk = tid >> 6, c = tid & 63;
    int b0 = isk ? (128 + 2 * c) : (2 * c);
    float s_ = partials[2 * b0] + partials[2 * b0 + 2];
    float q_ = partials[2 * b0 + 1] + partials[2 * b0 + 3];
    float m = s_ * (1.0f / NPOS);
    float var = q_ * (1.0f / NPOS) - m * m;
    stl[isk * 128 + c] = m;
    stl[isk * 128 + 64 + c] = rsqrtf(var + 1e-5f);
  }
  if (tid < 64) bol[tid] = bo[tid];

  // ---------------- Phase B: MFMA projections, 4 tiles/block ----------------
  short* xa  = (short*)scratch;              // 64x72
  short* ob  = (short*)(scratch + 9216);     // 64x72
  short* wbk = (short*)(scratch + 18432);    // 64x72
  short* wbv = (short*)(scratch + 27648);
  short* wbq = (short*)(scratch + 36864);
  {
    int c = tid >> 2, j0 = (tid & 3) * 16;
#define LOADW(dst, W)                                                          \
    {                                                                          \
      const float4* wr = (const float4*)((W) + c * 64 + j0);                   \
      float4 w0 = wr[0], w1 = wr[1], w2 = wr[2], w3 = wr[3];                   \
      float wv16[16] = {w0.x, w0.y, w0.z, w0.w, w1.x, w1.y, w1.z, w1.w,        \
                        w2.x, w2.y, w2.z, w2.w, w3.x, w3.y, w3.z, w3.w};       \
      _Pragma("unroll") for (int u = 0; u < 16; u++)                           \
          dst[(j0 + u) * 72 + c] = f2bs(wv16[u]);                              \
    }
    LOADW(wbk, Wk)
    LOADW(wbv, Wv)
    LOADW(wbq, Wq)
#undef LOADW
  }
  __syncthreads();

  int wv_ = tid >> 6, lane = tid & 63, quad = lane >> 4, l15 = lane & 15;
  int orow0 = wv_ * 16 + quad * 4;
  const float scale = 0.35355339059327373f;  // 8^-0.5

  for (int t = 0; t < 4; t++) {
    int tile = ((b & 7) << 7) + ((b >> 3) << 2) + t;
    int p0 = tile * 64;
    for (int ii = tid; ii < 512; ii += 256) {
      int c = ii >> 3, t0 = (ii & 7) * 8;
      short8 v8 = *(const short8*)(xu + (size_t)c * NPOS + p0 + t0);
      float m = stl[c], r = stl[64 + c];
#pragma unroll
      for (int u = 0; u < 8; u++)
        xa[(t0 + u) * 72 + c] = f2bs((bs2f(v8[u]) - m) * r);
    }
    __syncthreads();
    const short* arow = &xa[(wv_ * 16 + l15) * 72 + quad * 8];
#define MFMA_PASS(WB, BIAS, SC)                                                \
    {                                                                          \
      short8 a0 = *(const short8*)(arow);                                      \
      short8 a1 = *(const short8*)(arow + 32);                                 \
      _Pragma("unroll") for (int nt = 0; nt < 4; nt++) {                       \
        const short* brow = &WB[(nt * 16 + l15) * 72 + quad * 8];              \
        short8 b0 = *(const short8*)(brow);                                    \
        short8 b1 = *(const short8*)(brow + 32);                               \
        f32x4 acc = {0.f, 0.f, 0.f, 0.f};                                      \
        acc = __builtin_amdgcn_mfma_f32_16x16x32_bf16(a0, b0, acc, 0, 0, 0);   \
        acc = __builtin_amdgcn_mfma_f32_16x16x32_bf16(a1, b1, acc, 0, 0, 0);   \
        float bval = BIAS[nt * 16 + l15];                                      \
        _Pragma("unroll") for (int r = 0; r < 4; r++)                          \
            ob[(orow0 + r) * 72 + nt * 16 + l15] = f2bs((acc[r] + bval) * SC); \
      }                                                                        \
    }
#define STORE_OB(DST)                                                          \
    {                                                                          \
      int row = tid >> 2, col0 = (tid & 3) * 16;                               \
      short8 o0 = *(const short8*)(&ob[row * 72 + col0]);                      \
      short8 o1 = *(const short8*)(&ob[row * 72 + col0 + 8]);                  \
      *(short8*)(DST + (size_t)(p0 + row) * 64 + col0) = o0;                   \
      *(short8*)(DST + (size_t)(p0 + row) * 64 + col0 + 8) = o1;               \
    }
    MFMA_PASS(wbk, bk, 1.0f)
    __syncthreads();
    STORE_OB(kbuf)
    __syncthreads();
    MFMA_PASS(wbv, bv, 1.0f)
    __syncthreads();
    STORE_OB(vbuf)
    for (int ii = tid; ii < 1024; ii += 256) {
      int c = ii >> 4, t0 = (ii & 15) * 4;
      float4 v = *(const float4*)(skip + (size_t)c * NPOS + p0 + t0);
      float m = stl[128 + c], r = stl[192 + c];
      xa[(t0 + 0) * 72 + c] = f2bs((v.x - m) * r);
      xa[(t0 + 1) * 72 + c] = f2bs((v.y - m) * r);
      xa[(t0 + 2) * 72 + c] = f2bs((v.z - m) * r);
      xa[(t0 + 3) * 72 + c] = f2bs((v.w - m) * r);
    }
    __syncthreads();
    MFMA_PASS(wbq, bq, scale)
    __syncthreads();
    STORE_OB(qbuf)
    __syncthreads();
#undef MFMA_PASS
#undef STORE_OB
  }

  gbar(bar + 1, 256);

  // ---------------- Phase C: flat-27 attention + out-proj ----------------
  float* rp = (float*)scratch;               // 1000 f
  float* wo = (float*)(scratch + 4000);      // 4096 f
  float* oT = (float*)(scratch + 20384);     // 64*65 f
  for (int i = tid; i < 1000; i += 256) rp[i] = rpb[i];
  for (int i = tid; i < 1024; i += 256)
    ((float4*)wo)[i] = ((const float4*)Wo)[i];
  __syncthreads();

  int head = tid & 7, pp = tid >> 3;  // pp 0..31
  for (int t = 0; t < 4; t++) {
    int tile = ((b & 7) << 7) + ((b >> 3) << 2) + t;
    for (int half = 0; half < 2; half++) {
      int p = tile * 64 + half * 32 + pp;
      int h = p >> 10, w = (p >> 4) & 63, z = p & 15;
      short8 q8 = *(const short8*)(qbuf + (size_t)p * 64 + head * 8);
      float q[8];
#pragma unroll
      for (int d = 0; d < 8; d++) q[d] = bs2f(q8[d]);
      int sh = h - 1; if (sh < 0) sh = 0; if (sh > 61) sh = 61;
      int sw = w - 1; if (sw < 0) sw = 0; if (sw > 61) sw = 61;
      int sz = z - 1; if (sz < 0) sz = 0; if (sz > 13) sz = 13;
      const bf16* kb = kbuf + (size_t)(sh * 1024 + sw * 16 + sz) * 64 + head * 8;
      const bf16* vb = vbuf + (size_t)(sh * 1024 + sw * 16 + sz) * 64 + head * 8;
      int rbase =
          ((sh - h + 2) * 5 + (sw - w + 2)) * 5 + (sz - z + 2) + head * 125;
      float s[27];
#pragma unroll
      for (int j = 0; j < 27; j++) {
        int kh = j / 9, kw = (j % 9) / 3, kz = j % 3;
        int coff = (kh * 1024 + kw * 16 + kz) * 64;
        short8 k8 = *(const short8*)(kb + coff);
        float sv = q[0] * bs2f(k8[0]) + q[1] * bs2f(k8[1]) +
                   q[2] * bs2f(k8[2]) + q[3] * bs2f(k8[3]) +
                   q[4] * bs2f(k8[4]) + q[5] * bs2f(k8[5]) +
                   q[6] * bs2f(k8[6]) + q[7] * bs2f(k8[7]);
        s[j] = sv + rp[rbase + (kh * 5 + kw) * 5 + kz];
      }
      float M = s[26];
#pragma unroll
      for (int j = 0; j < 13; j++) M = fmaxf(M, fmaxf(s[2 * j], s[2 * j + 1]));
      float lrun = 0.f;
      float oa[8];
#pragma unroll
      for (int d = 0; d < 8; d++) oa[d] = 0.f;
#pragma unroll
      for (int j = 0; j < 27; j++) {
        int kh = j / 9, kw = (j % 9) / 3, kz = j % 3;
        int coff = (kh * 1024 + kw * 16 + kz) * 64;
        short8 v8 = *(const short8*)(vb + coff);
        float pw = __expf(s[j] - M);
        lrun += pw;
#pragma unroll
        for (int d = 0; d < 8; d++) oa[d] += pw * bs2f(v8[d]);
      }
      float inv = 1.0f / lrun;
#pragma unroll
      for (int d = 0; d < 8; d++)
        oT[(half * 32 + pp) * 65 + head * 8 + d] = oa[d] * inv;
    }
    __syncthreads();
    // out-proj: wave wid -> channels wid*16..+15, lane l = position
    int wid = tid >> 6, l = tid & 63;
    int p0 = tile * 64;
    float acc[16];
#pragma unroll
    for (int u = 0; u < 16; u++) acc[u] = bol[wid * 16 + u];
    for (int j = 0; j < 64; j++) {
      float ov = oT[l * 65 + j];
      const float4* wr4 = (const float4*)&wo[j * 64 + wid * 16];
      float4 w0 = wr4[0], w1 = wr4[1], w2 = wr4[2], w3 = wr4[3];
      acc[0] += ov * w0.x;  acc[1] += ov * w0.y;
      acc[2] += ov * w0.z;  acc[3] += ov * w0.w;
      acc[4] += ov * w1.x;  acc[5] += ov * w1.y;
      acc[6] += ov * w1.z;  acc[7] += ov * w1.w;
      acc[8] += ov * w2.x;  acc[9] += ov * w2.y;
      acc[10] += ov * w2.z; acc[11] += ov * w2.w;
      acc[12] += ov * w3.x; acc[13] += ov * w3.y;
      acc[14] += ov * w3.z; acc[15] += ov * w3.w;
    }
#pragma unroll
    for (int u = 0; u < 16; u++)
      out[(size_t)(wid * 16 + u) * NPOS + p0 + l] = acc[u];
    __syncthreads();
  }
}

extern "C" void kernel_launch(void* const* d_in, const int* in_sizes, int n_in,
                              void* d_out, int out_size, void* d_ws, size_t ws_size,
                              hipStream_t stream) {
  const float* x    = (const float*)d_in[0];
  const float* skip = (const float*)d_in[1];
  const float* Wq   = (const float*)d_in[2];
  const float* bq   = (const float*)d_in[3];
  const float* Wk   = (const float*)d_in[4];
  const float* bk   = (const float*)d_in[5];
  const float* Wv   = (const float*)d_in[6];
  const float* bv   = (const float*)d_in[7];
  const float* Wo   = (const float*)d_in[8];
  const float* bo   = (const float*)d_in[9];
  const float* rpb  = (const float*)d_in[10];

  bf16* xu        = (bf16*)d_ws;                                 // 8 MB
  bf16* kbuf      = (bf16*)((char*)d_ws + ((size_t)8 << 20));    // 8 MB
  bf16* vbuf      = (bf16*)((char*)d_ws + ((size_t)16 << 20));   // 8 MB
  bf16* qbuf      = (bf16*)((char*)d_ws + ((size_t)24 << 20));   // 8 MB
  float* partials = (float*)((char*)d_ws + ((size_t)32 << 20));  // 512 fp32
  unsigned* bar   = (unsigned*)((char*)d_ws + ((size_t)32 << 20) + 4096);
  float* out = (float*)d_out;

  hipLaunchKernelGGL(k_init, dim3(1), dim3(64), 0, stream, bar);
  hipLaunchKernelGGL(k_fused, dim3(256), dim3(256), 0, stream, x, skip, Wq, bq,
                     Wk, bk, Wv, bv, Wo, bo, rpb, xu, kbuf, vbuf, qbuf,
                     partials, bar, out);
}